// Round 1
// baseline (538.648 us; speedup 1.0000x reference)
//
#include <hip/hip_runtime.h>

#define D_ 1024
#define T_ 2048
#define B_ 2
#define H_ 16
#define MLP_ 4096
#define NTOK (B_*T_)   // 4096
#define QG 256         // global q-rows per batch (T/8)

typedef float f32x4 __attribute__((ext_vector_type(4)));
typedef __bf16 bf16x8 __attribute__((ext_vector_type(8)));

__device__ __forceinline__ unsigned short f2bf(float f) {
  unsigned int u = __float_as_uint(f);
  u += 0x7fff + ((u >> 16) & 1);
  return (unsigned short)(u >> 16);
}
__device__ __forceinline__ float bf2f(unsigned short s) {
  return __uint_as_float(((unsigned int)s) << 16);
}

__device__ __forceinline__ float wave_sum(float v) {
  for (int o = 32; o > 0; o >>= 1) v += __shfl_down(v, o, 64);
  return v;
}
__device__ __forceinline__ float wave_max(float v) {
  for (int o = 32; o > 0; o >>= 1) v = fmaxf(v, __shfl_down(v, o, 64));
  return v;
}

// ---------------- weight cast f32 -> bf16 (vectorized x4) ----------------
__global__ void cast_bf16_kernel(const float* __restrict__ in,
                                 unsigned short* __restrict__ out, int n4) {
  int i = blockIdx.x * 256 + threadIdx.x;
  if (i < n4) {
    float4 v = ((const float4*)in)[i];
    ushort4 o;
    o.x = f2bf(v.x); o.y = f2bf(v.y); o.z = f2bf(v.z); o.w = f2bf(v.w);
    ((ushort4*)out)[i] = o;
  }
}

// ---------------- LayerNorm (one block per row of D=1024), out bf16 ------
__global__ void ln_kernel(const float* __restrict__ x, const float* __restrict__ g,
                          const float* __restrict__ b, unsigned short* __restrict__ out) {
  int row = blockIdx.x;
  int tid = threadIdx.x;
  int wave = tid >> 6, lane = tid & 63;
  float4 v = ((const float4*)(x + (size_t)row * D_))[tid];
  float s  = v.x + v.y + v.z + v.w;
  float s2 = v.x*v.x + v.y*v.y + v.z*v.z + v.w*v.w;
  s = wave_sum(s); s2 = wave_sum(s2);
  __shared__ float r1[4], r2[4];
  if (lane == 0) { r1[wave] = s; r2[wave] = s2; }
  __syncthreads();
  float ts  = r1[0] + r1[1] + r1[2] + r1[3];
  float ts2 = r2[0] + r2[1] + r2[2] + r2[3];
  float mean = ts * (1.0f / D_);
  float var  = ts2 * (1.0f / D_) - mean * mean;
  float rs = rsqrtf(var + 1e-5f);
  float4 gv = ((const float4*)g)[tid];
  float4 bv = ((const float4*)b)[tid];
  ushort4 o;
  o.x = f2bf((v.x - mean) * rs * gv.x + bv.x);
  o.y = f2bf((v.y - mean) * rs * gv.y + bv.y);
  o.z = f2bf((v.z - mean) * rs * gv.z + bv.z);
  o.w = f2bf((v.w - mean) * rs * gv.w + bv.w);
  ((ushort4*)(out + (size_t)row * D_))[tid] = o;
}

// ---------------- Generic batched bf16 MFMA GEMM -------------------------
// C[m,n] = sum_k A[m,k] * B[n,k]   (both operands K-contiguous, "W layout")
// EPI: 0 = f32 out + bias          (QKV)
//      1 = f32 out + bias + res    (out-proj residual / final residual)
//      2 = bf16 out, gelu(acc+bias)(MLP1)
//      3 = bf16 out, acc*scale     (scores)
//      4 = bf16 out, acc           (PV)
template<int EPI>
__global__ __launch_bounds__(256)
void gemm_kernel(const unsigned short* __restrict__ A, int lda, size_t sA,
                 const unsigned short* __restrict__ Bm, int ldb, size_t sB,
                 void* __restrict__ Cv, int ldc, size_t sC,
                 const float* __restrict__ bias,
                 const float* __restrict__ res,
                 int M, int N, int K, float scale) {
  __shared__ __align__(16) unsigned short As[128 * 40];
  __shared__ __align__(16) unsigned short Bs[128 * 40];
  const int bz = blockIdx.z;
  const unsigned short* Ab = A  + (size_t)bz * sA;
  const unsigned short* Bb = Bm + (size_t)bz * sB;
  const int m0 = blockIdx.y * 128;
  const int n0 = blockIdx.x * 128;
  const int tid = threadIdx.x;
  const int lane = tid & 63, wave = tid >> 6;
  const int wm = (wave >> 1) * 64, wn = (wave & 1) * 64;
  const int fr = lane & 15, fk = (lane >> 4) * 8;
  f32x4 acc[4][4] = {};

  for (int ko = 0; ko < K; ko += 32) {
    __syncthreads();
#pragma unroll
    for (int it = 0; it < 2; ++it) {
      int linear = it * 256 + tid;      // 0..511
      int row = linear >> 2;            // 0..127
      int kc = (linear & 3) << 3;       // 0,8,16,24
      *(uint4*)&As[row * 40 + kc] =
          *(const uint4*)(Ab + (size_t)(m0 + row) * lda + ko + kc);
      uint4 bvv = {0u, 0u, 0u, 0u};
      if (n0 + row < N)
        bvv = *(const uint4*)(Bb + (size_t)(n0 + row) * ldb + ko + kc);
      *(uint4*)&Bs[row * 40 + kc] = bvv;
    }
    __syncthreads();
    bf16x8 af[4], bfr[4];
#pragma unroll
    for (int i = 0; i < 4; ++i)
      af[i] = *(const bf16x8*)&As[(wm + i * 16 + fr) * 40 + fk];
#pragma unroll
    for (int j = 0; j < 4; ++j)
      bfr[j] = *(const bf16x8*)&Bs[(wn + j * 16 + fr) * 40 + fk];
#pragma unroll
    for (int i = 0; i < 4; ++i)
#pragma unroll
      for (int j = 0; j < 4; ++j)
        acc[i][j] = __builtin_amdgcn_mfma_f32_16x16x32_bf16(af[i], bfr[j], acc[i][j], 0, 0, 0);
  }

  const int col = lane & 15, rbase = (lane >> 4) * 4;
#pragma unroll
  for (int i = 0; i < 4; ++i) {
#pragma unroll
    for (int j = 0; j < 4; ++j) {
      int gn = n0 + wn + j * 16 + col;
      if (gn >= N) continue;
      int gmb = m0 + wm + i * 16 + rbase;
      float bv = (EPI <= 2) ? bias[gn] : 0.0f;
#pragma unroll
      for (int r = 0; r < 4; ++r) {
        int gm = gmb + r;
        float v = acc[i][j][r] + bv;
        size_t ci = (size_t)bz * sC + (size_t)gm * ldc + gn;
        if (EPI == 0) {
          ((float*)Cv)[ci] = v;
        } else if (EPI == 1) {
          ((float*)Cv)[ci] = v + res[(size_t)gm * ldc + gn];
        } else if (EPI == 2) {
          float gl = 0.5f * v * (1.0f + erff(v * 0.70710678118f));
          ((unsigned short*)Cv)[ci] = f2bf(gl);
        } else if (EPI == 3) {
          ((unsigned short*)Cv)[ci] = f2bf(v * scale);
        } else {
          ((unsigned short*)Cv)[ci] = f2bf(v);
        }
      }
    }
  }
}

// ---------------- split q (global rows only) and k into bf16 head-major ---
__global__ void qg_kernel(const float* __restrict__ qkv, unsigned short* __restrict__ Qg) {
  int idx = blockIdx.x * 256 + threadIdx.x;  // B*H*QG*64 = 2^19
  int d = idx & 63;
  int qi = (idx >> 6) & (QG - 1);
  int h = (idx >> 14) & (H_ - 1);
  int b = idx >> 18;
  Qg[idx] = f2bf(qkv[((size_t)(b * T_ + qi * 8)) * (3 * D_) + h * 64 + d]);
}

__global__ void kh_kernel(const float* __restrict__ qkv, unsigned short* __restrict__ Kh) {
  int idx = blockIdx.x * 256 + threadIdx.x;  // B*H*T*64 = 2^22
  int d = idx & 63;
  int t = (idx >> 6) & (T_ - 1);
  int h = (idx >> 17) & (H_ - 1);
  int b = idx >> 21;
  Kh[idx] = f2bf(qkv[((size_t)(b * T_ + t)) * (3 * D_) + D_ + h * 64 + d]);
}

// ---------------- V transpose: qkv v-part -> Vt[bh][d][t] bf16 ------------
__global__ void vtrans_kernel(const float* __restrict__ qkv, unsigned short* __restrict__ Vt) {
  int blk = blockIdx.x;          // B*H*(T/64) = 1024
  int tchunk = blk & 31;
  int bh = blk >> 5;
  int h = bh & (H_ - 1), b = bh >> 4;
  int t0 = tchunk * 64;
  __shared__ float ls[64][65];
  int tid = threadIdx.x;
#pragma unroll
  for (int it = 0; it < 16; ++it) {
    int linear = it * 256 + tid;
    int d = linear & 63, tl = linear >> 6;
    ls[d][tl] = qkv[((size_t)(b * T_ + t0 + tl)) * (3 * D_) + 2 * D_ + h * 64 + d];
  }
  __syncthreads();
#pragma unroll
  for (int it = 0; it < 16; ++it) {
    int linear = it * 256 + tid;
    int tl = linear & 63, d = linear >> 6;
    Vt[((size_t)(bh * 64 + d)) * T_ + t0 + tl] = f2bf(ls[d][tl]);
  }
}

// ---------------- row softmax over S (in place, bf16), rows of T=2048 -----
__global__ void softmax_kernel(unsigned short* __restrict__ S) {
  size_t row = blockIdx.x;
  unsigned short* Sr = S + row * (size_t)T_;
  int tid = threadIdx.x;
  int wave = tid >> 6, lane = tid & 63;
  __shared__ float red[4];
  float vals[8];
  float mx = -1e30f;
#pragma unroll
  for (int i = 0; i < 8; ++i) {
    vals[i] = bf2f(Sr[i * 256 + tid]);
    mx = fmaxf(mx, vals[i]);
  }
  mx = wave_max(mx);
  if (lane == 0) red[wave] = mx;
  __syncthreads();
  mx = fmaxf(fmaxf(red[0], red[1]), fmaxf(red[2], red[3]));
  __syncthreads();
  float sum = 0.f;
#pragma unroll
  for (int i = 0; i < 8; ++i) { vals[i] = expf(vals[i] - mx); sum += vals[i]; }
  sum = wave_sum(sum);
  if (lane == 0) red[wave] = sum;
  __syncthreads();
  sum = red[0] + red[1] + red[2] + red[3];
  float inv = 1.0f / sum;
#pragma unroll
  for (int i = 0; i < 8; ++i) Sr[i * 256 + tid] = f2bf(vals[i] * inv);
}

// ---------------- assemble o: global rows from Og, others o = v -----------
__global__ void assemble_o_kernel(const float* __restrict__ qkv,
                                  const unsigned short* __restrict__ Og,
                                  unsigned short* __restrict__ o) {
  int idx = blockIdx.x * 256 + threadIdx.x;  // NTOK*D = 2^22
  int c = idx & (D_ - 1);
  int t = (idx >> 10) & (T_ - 1);
  int b = idx >> 21;
  if (t & 7) {
    o[idx] = f2bf(qkv[((size_t)(b * T_ + t)) * (3 * D_) + 2 * D_ + c]);
  } else {
    int h = c >> 6, d = c & 63;
    o[idx] = Og[(((size_t)(b * H_ + h)) * QG + (t >> 3)) * 64 + d];
  }
}

extern "C" void kernel_launch(void* const* d_in, const int* in_sizes, int n_in,
                              void* d_out, int out_size, void* d_ws, size_t ws_size,
                              hipStream_t stream) {
  const float* x     = (const float*)d_in[0];
  const float* w_in  = (const float*)d_in[1];
  const float* b_in  = (const float*)d_in[2];
  const float* w_out = (const float*)d_in[3];
  const float* b_out = (const float*)d_in[4];
  const float* w1    = (const float*)d_in[5];
  const float* b1    = (const float*)d_in[6];
  const float* w2    = (const float*)d_in[7];
  const float* b2    = (const float*)d_in[8];
  const float* ln1_g = (const float*)d_in[9];
  const float* ln1_b = (const float*)d_in[10];
  const float* ln2_g = (const float*)d_in[11];
  const float* ln2_b = (const float*)d_in[12];
  float* out = (float*)d_out;

  char* ws = (char*)d_ws;
  size_t off = 0;
  auto alloc = [&](size_t bytes) -> void* {
    void* p = ws + off;
    off += (bytes + 255) & ~(size_t)255;
    return p;
  };
  unsigned short* xn    = (unsigned short*)alloc((size_t)NTOK * D_ * 2);
  float*          qkv   = (float*)         alloc((size_t)NTOK * 3 * D_ * 4);
  unsigned short* w_inb = (unsigned short*)alloc((size_t)3 * D_ * D_ * 2);
  unsigned short* w_outb= (unsigned short*)alloc((size_t)D_ * D_ * 2);
  unsigned short* w1b   = (unsigned short*)alloc((size_t)MLP_ * D_ * 2);
  unsigned short* w2b   = (unsigned short*)alloc((size_t)D_ * MLP_ * 2);
  unsigned short* Qg    = (unsigned short*)alloc((size_t)B_ * H_ * QG * 64 * 2);
  unsigned short* Kh    = (unsigned short*)alloc((size_t)B_ * H_ * T_ * 64 * 2);
  unsigned short* Vt    = (unsigned short*)alloc((size_t)B_ * H_ * 64 * T_ * 2);
  unsigned short* S     = (unsigned short*)alloc((size_t)B_ * H_ * QG * T_ * 2);
  unsigned short* Og    = (unsigned short*)alloc((size_t)B_ * H_ * QG * 64 * 2);
  unsigned short* o     = (unsigned short*)alloc((size_t)NTOK * D_ * 2);
  float*          x1    = (float*)         alloc((size_t)NTOK * D_ * 4);
  unsigned short* xn2   = (unsigned short*)alloc((size_t)NTOK * D_ * 2);
  unsigned short* h     = (unsigned short*)alloc((size_t)NTOK * MLP_ * 2);

  // 1. weight casts
  cast_bf16_kernel<<<3072, 256, 0, stream>>>(w_in,  w_inb,  3 * D_ * D_ / 4);
  cast_bf16_kernel<<<1024, 256, 0, stream>>>(w_out, w_outb, D_ * D_ / 4);
  cast_bf16_kernel<<<4096, 256, 0, stream>>>(w1,    w1b,    MLP_ * D_ / 4);
  cast_bf16_kernel<<<4096, 256, 0, stream>>>(w2,    w2b,    D_ * MLP_ / 4);

  // 2. LN1
  ln_kernel<<<NTOK, 256, 0, stream>>>(x, ln1_g, ln1_b, xn);

  // 3. QKV = xn @ w_in^T + b_in   -> f32 [4096, 3072]
  gemm_kernel<0><<<dim3(24, 32, 1), 256, 0, stream>>>(
      xn, D_, 0, w_inb, D_, 0, qkv, 3 * D_, 0, b_in, nullptr,
      NTOK, 3 * D_, D_, 1.0f);

  // 4. split heads
  qg_kernel<<<2048, 256, 0, stream>>>(qkv, Qg);
  kh_kernel<<<16384, 256, 0, stream>>>(qkv, Kh);
  vtrans_kernel<<<1024, 256, 0, stream>>>(qkv, Vt);

  // 5. S = Qg Kh^T / 8   (batched over 32 bh)
  gemm_kernel<3><<<dim3(16, 2, 32), 256, 0, stream>>>(
      Qg, 64, (size_t)QG * 64, Kh, 64, (size_t)T_ * 64,
      S, T_, (size_t)QG * T_, nullptr, nullptr,
      QG, T_, 64, 0.125f);

  // 6. softmax rows
  softmax_kernel<<<B_ * H_ * QG, 256, 0, stream>>>(S);

  // 7. Og = P V   (batched, N=64)
  gemm_kernel<4><<<dim3(1, 2, 32), 256, 0, stream>>>(
      S, T_, (size_t)QG * T_, Vt, T_, (size_t)64 * T_,
      Og, 64, (size_t)QG * 64, nullptr, nullptr,
      QG, 64, T_, 1.0f);

  // 8. assemble o
  assemble_o_kernel<<<16384, 256, 0, stream>>>(qkv, Og, o);

  // 9. x1 = x + o @ w_out^T + b_out   -> f32
  gemm_kernel<1><<<dim3(8, 32, 1), 256, 0, stream>>>(
      o, D_, 0, w_outb, D_, 0, x1, D_, 0, b_out, x,
      NTOK, D_, D_, 1.0f);

  // 10. LN2
  ln_kernel<<<NTOK, 256, 0, stream>>>(x1, ln2_g, ln2_b, xn2);

  // 11. h = gelu(xn2 @ w1^T + b1)  -> bf16 [4096, 4096]
  gemm_kernel<2><<<dim3(32, 32, 1), 256, 0, stream>>>(
      xn2, D_, 0, w1b, D_, 0, h, MLP_, 0, b1, nullptr,
      NTOK, MLP_, D_, 1.0f);

  // 12. out = x1 + h @ w2^T + b2  -> f32
  gemm_kernel<1><<<dim3(8, 32, 1), 256, 0, stream>>>(
      h, MLP_, 0, w2b, MLP_, 0, out, D_, 0, b2, x1,
      NTOK, D_, MLP_, 1.0f);
}

// Round 2
// 441.549 us; speedup vs baseline: 1.2199x; 1.2199x over previous
//
#include <hip/hip_runtime.h>

#define D_ 1024
#define T_ 2048
#define B_ 2
#define H_ 16
#define MLP_ 4096
#define NTOK (B_*T_)   // 4096
#define QG 256         // global q-rows per batch (T/8)

typedef float f32x4 __attribute__((ext_vector_type(4)));
typedef __bf16 bf16x8 __attribute__((ext_vector_type(8)));

__device__ __forceinline__ unsigned short f2bf(float f) {
  unsigned int u = __float_as_uint(f);
  u += 0x7fff + ((u >> 16) & 1);
  return (unsigned short)(u >> 16);
}
__device__ __forceinline__ float bf2f(unsigned short s) {
  return __uint_as_float(((unsigned int)s) << 16);
}

__device__ __forceinline__ float wave_sum(float v) {
  for (int o = 32; o > 0; o >>= 1) v += __shfl_down(v, o, 64);
  return v;
}
__device__ __forceinline__ float wave_max(float v) {
  for (int o = 32; o > 0; o >>= 1) v = fmaxf(v, __shfl_down(v, o, 64));
  return v;
}

// async global->LDS, 16B per lane; LDS dest = wave-uniform base + lane*16
__device__ __forceinline__ void gload16(const unsigned short* g, unsigned short* l) {
  __builtin_amdgcn_global_load_lds(
      (const __attribute__((address_space(1))) void*)g,
      (__attribute__((address_space(3))) void*)l, 16, 0, 0);
}

// ---------------- weight cast f32 -> bf16 (vectorized x4) ----------------
__global__ void cast_bf16_kernel(const float* __restrict__ in,
                                 unsigned short* __restrict__ out, int n4) {
  int i = blockIdx.x * 256 + threadIdx.x;
  if (i < n4) {
    float4 v = ((const float4*)in)[i];
    ushort4 o;
    o.x = f2bf(v.x); o.y = f2bf(v.y); o.z = f2bf(v.z); o.w = f2bf(v.w);
    ((ushort4*)out)[i] = o;
  }
}

// ---------------- LayerNorm (one block per row of D=1024), out bf16 ------
__global__ void ln_kernel(const float* __restrict__ x, const float* __restrict__ g,
                          const float* __restrict__ b, unsigned short* __restrict__ out) {
  int row = blockIdx.x;
  int tid = threadIdx.x;
  int wave = tid >> 6, lane = tid & 63;
  float4 v = ((const float4*)(x + (size_t)row * D_))[tid];
  float s  = v.x + v.y + v.z + v.w;
  float s2 = v.x*v.x + v.y*v.y + v.z*v.z + v.w*v.w;
  s = wave_sum(s); s2 = wave_sum(s2);
  __shared__ float r1[4], r2[4];
  if (lane == 0) { r1[wave] = s; r2[wave] = s2; }
  __syncthreads();
  float ts  = r1[0] + r1[1] + r1[2] + r1[3];
  float ts2 = r2[0] + r2[1] + r2[2] + r2[3];
  float mean = ts * (1.0f / D_);
  float var  = ts2 * (1.0f / D_) - mean * mean;
  float rs = rsqrtf(var + 1e-5f);
  float4 gv = ((const float4*)g)[tid];
  float4 bv = ((const float4*)b)[tid];
  ushort4 o;
  o.x = f2bf((v.x - mean) * rs * gv.x + bv.x);
  o.y = f2bf((v.y - mean) * rs * gv.y + bv.y);
  o.z = f2bf((v.z - mean) * rs * gv.z + bv.z);
  o.w = f2bf((v.w - mean) * rs * gv.w + bv.w);
  ((ushort4*)(out + (size_t)row * D_))[tid] = o;
}

// ---------------- Generic batched bf16 MFMA GEMM (m97-style staging) -----
// C[m,n] = sum_k A[m,k] * B[n,k]
// EPI: 0 = f32 out + bias
//      1 = f32 out + bias + res
//      2 = bf16 out, gelu(acc+bias)
//      3 = bf16 out, acc*scale
//      4 = bf16 out, acc
//      5 = f32 atomicAdd (split-K PV; z = bh*4 + kchunk)
//      6 = bf16 out + bias
// SWIZ: 0 = x-fast, 1 = y-fast (skinny N: same-A blocks share an XCD),
//       2 = 2x4 super-tiles (needs nx%2==0, ny%4==0, (nx*ny/8)%8==0)
template<int EPI, int SWIZ>
__global__ __launch_bounds__(256)
void gemm_kernel(const unsigned short* __restrict__ A, int lda, size_t sA,
                 const unsigned short* __restrict__ Bm, int ldb, size_t sB,
                 void* __restrict__ Cv, int ldc, size_t sC,
                 const float* __restrict__ bias,
                 const float* __restrict__ res,
                 int M, int N, int K, float scale, int nx, int ny) {
  // unpadded 128x32 tiles, 16B chunk c_lds holds global chunk c_lds ^ (row&3)
  __shared__ __align__(16) unsigned short As[128 * 32];
  __shared__ __align__(16) unsigned short Bs[128 * 32];
  const int flat = blockIdx.x;
  int bx, by;
  if (SWIZ == 1) {
    bx = flat / ny; by = flat - bx * ny;
  } else if (SWIZ == 2) {
    const int sxc = nx >> 1;
    const int nSuper = sxc * (ny >> 2);
    int s = flat % nSuper, pos = flat / nSuper;
    int sx = s % sxc, sy = s / sxc;
    bx = sx * 2 + (pos & 1);
    by = sy * 4 + (pos >> 1);
  } else {
    bx = flat % nx; by = flat / nx;
  }
  const int bz = blockIdx.z;
  const int batch = (EPI == 5) ? (bz >> 2) : bz;
  const int kOff  = (EPI == 5) ? ((bz & 3) * K) : 0;
  const unsigned short* Ab = A  + (size_t)batch * sA + kOff;
  const unsigned short* Bb = Bm + (size_t)batch * sB + kOff;
  const int m0 = by * 128;
  const int n0 = bx * 128;
  const int tid = threadIdx.x;
  const int lane = tid & 63, wave = tid >> 6;
  const int wm = (wave >> 1) * 64, wn = (wave & 1) * 64;
  const int fr = lane & 15, q = lane >> 4;
  f32x4 acc[4][4] = {};

  for (int ko = 0; ko < K; ko += 32) {
    __syncthreads();
#pragma unroll
    for (int p = 0; p < 2; ++p) {
      int linear = p * 256 + tid;       // 0..511
      int r = linear >> 2;              // 0..127
      int cg = (linear & 3) ^ (r & 3);  // swizzled global 16B chunk
      gload16(Ab + (size_t)(m0 + r) * lda + ko + cg * 8, &As[linear * 8]);
      int rb = n0 + r; if (rb >= N) rb = N - 1;   // clamp (garbage cols discarded)
      gload16(Bb + (size_t)rb * ldb + ko + cg * 8, &Bs[linear * 8]);
    }
    __syncthreads();
    bf16x8 af[4], bfr[4];
#pragma unroll
    for (int i = 0; i < 4; ++i)
      af[i] = *(const bf16x8*)&As[(wm + i * 16 + fr) * 32 + ((q ^ (fr & 3)) << 3)];
#pragma unroll
    for (int j = 0; j < 4; ++j)
      bfr[j] = *(const bf16x8*)&Bs[(wn + j * 16 + fr) * 32 + ((q ^ (fr & 3)) << 3)];
#pragma unroll
    for (int i = 0; i < 4; ++i)
#pragma unroll
      for (int j = 0; j < 4; ++j)
        acc[i][j] = __builtin_amdgcn_mfma_f32_16x16x32_bf16(af[i], bfr[j], acc[i][j], 0, 0, 0);
  }

  const int col = lane & 15, rbase = (lane >> 4) * 4;
#pragma unroll
  for (int i = 0; i < 4; ++i) {
#pragma unroll
    for (int j = 0; j < 4; ++j) {
      int gn = n0 + wn + j * 16 + col;
      if (gn >= N) continue;
      int gmb = m0 + wm + i * 16 + rbase;
      float bv = (EPI <= 2 || EPI == 6) ? bias[gn] : 0.0f;
#pragma unroll
      for (int r = 0; r < 4; ++r) {
        int gm = gmb + r;
        float v = acc[i][j][r] + bv;
        size_t ci = (size_t)batch * sC + (size_t)gm * ldc + gn;
        if (EPI == 0) {
          ((float*)Cv)[ci] = v;
        } else if (EPI == 1) {
          ((float*)Cv)[ci] = v + res[(size_t)gm * ldc + gn];
        } else if (EPI == 2) {
          float gl = 0.5f * v * (1.0f + erff(v * 0.70710678118f));
          ((unsigned short*)Cv)[ci] = f2bf(gl);
        } else if (EPI == 3) {
          ((unsigned short*)Cv)[ci] = f2bf(v * scale);
        } else if (EPI == 4) {
          ((unsigned short*)Cv)[ci] = f2bf(v);
        } else if (EPI == 5) {
          atomicAdd(&((float*)Cv)[ci], v);
        } else {
          ((unsigned short*)Cv)[ci] = f2bf(v);
        }
      }
    }
  }
}

// ---------------- split q (global rows only) and k, bf16 head-major ------
__global__ void qg_kernel(const unsigned short* __restrict__ qkv, unsigned short* __restrict__ Qg) {
  int idx = blockIdx.x * 256 + threadIdx.x;  // B*H*QG*64 = 2^19
  int d = idx & 63;
  int qi = (idx >> 6) & (QG - 1);
  int h = (idx >> 14) & (H_ - 1);
  int b = idx >> 18;
  Qg[idx] = qkv[((size_t)(b * T_ + qi * 8)) * (3 * D_) + h * 64 + d];
}

__global__ void kh_kernel(const unsigned short* __restrict__ qkv, unsigned short* __restrict__ Kh) {
  int idx = blockIdx.x * 256 + threadIdx.x;  // B*H*T*64 = 2^22
  int d = idx & 63;
  int t = (idx >> 6) & (T_ - 1);
  int h = (idx >> 17) & (H_ - 1);
  int b = idx >> 21;
  Kh[idx] = qkv[((size_t)(b * T_ + t)) * (3 * D_) + D_ + h * 64 + d];
}

// ---------------- V transpose: qkv v-part -> Vt[bh][d][t] bf16 -----------
__global__ void vtrans_kernel(const unsigned short* __restrict__ qkv, unsigned short* __restrict__ Vt) {
  int blk = blockIdx.x;          // B*H*(T/64) = 1024
  int tchunk = blk & 31;
  int bh = blk >> 5;
  int h = bh & (H_ - 1), b = bh >> 4;
  int t0 = tchunk * 64;
  __shared__ unsigned short ls[64][66];
  int tid = threadIdx.x;
#pragma unroll
  for (int it = 0; it < 16; ++it) {
    int linear = it * 256 + tid;
    int d = linear & 63, tl = linear >> 6;
    ls[d][tl] = qkv[((size_t)(b * T_ + t0 + tl)) * (3 * D_) + 2 * D_ + h * 64 + d];
  }
  __syncthreads();
#pragma unroll
  for (int it = 0; it < 16; ++it) {
    int linear = it * 256 + tid;
    int tl = linear & 63, d = linear >> 6;
    Vt[((size_t)(bh * 64 + d)) * T_ + t0 + tl] = ls[d][tl];
  }
}

// ---------------- row softmax over S (in place, bf16), rows of T=2048 ----
__global__ void softmax_kernel(unsigned short* __restrict__ S) {
  size_t row = blockIdx.x;
  unsigned short* Sr = S + row * (size_t)T_;
  int tid = threadIdx.x;
  int wave = tid >> 6, lane = tid & 63;
  __shared__ float red[4];
  float vals[8];
  float mx = -1e30f;
#pragma unroll
  for (int i = 0; i < 8; ++i) {
    vals[i] = bf2f(Sr[i * 256 + tid]);
    mx = fmaxf(mx, vals[i]);
  }
  mx = wave_max(mx);
  if (lane == 0) red[wave] = mx;
  __syncthreads();
  mx = fmaxf(fmaxf(red[0], red[1]), fmaxf(red[2], red[3]));
  __syncthreads();
  float sum = 0.f;
#pragma unroll
  for (int i = 0; i < 8; ++i) { vals[i] = expf(vals[i] - mx); sum += vals[i]; }
  sum = wave_sum(sum);
  if (lane == 0) red[wave] = sum;
  __syncthreads();
  sum = red[0] + red[1] + red[2] + red[3];
  float inv = 1.0f / sum;
#pragma unroll
  for (int i = 0; i < 8; ++i) Sr[i * 256 + tid] = f2bf(vals[i] * inv);
}

// ---------------- assemble o: global rows from Og (f32), others o = v ----
__global__ void assemble_o_kernel(const unsigned short* __restrict__ qkv,
                                  const float* __restrict__ Og,
                                  unsigned short* __restrict__ o) {
  int idx = blockIdx.x * 256 + threadIdx.x;  // NTOK*D = 2^22
  int c = idx & (D_ - 1);
  int t = (idx >> 10) & (T_ - 1);
  int b = idx >> 21;
  if (t & 7) {
    o[idx] = qkv[((size_t)(b * T_ + t)) * (3 * D_) + 2 * D_ + c];
  } else {
    int h = c >> 6, d = c & 63;
    o[idx] = f2bf(Og[(((size_t)(b * H_ + h)) * QG + (t >> 3)) * 64 + d]);
  }
}

extern "C" void kernel_launch(void* const* d_in, const int* in_sizes, int n_in,
                              void* d_out, int out_size, void* d_ws, size_t ws_size,
                              hipStream_t stream) {
  const float* x     = (const float*)d_in[0];
  const float* w_in  = (const float*)d_in[1];
  const float* b_in  = (const float*)d_in[2];
  const float* w_out = (const float*)d_in[3];
  const float* b_out = (const float*)d_in[4];
  const float* w1    = (const float*)d_in[5];
  const float* b1    = (const float*)d_in[6];
  const float* w2    = (const float*)d_in[7];
  const float* b2    = (const float*)d_in[8];
  const float* ln1_g = (const float*)d_in[9];
  const float* ln1_b = (const float*)d_in[10];
  const float* ln2_g = (const float*)d_in[11];
  const float* ln2_b = (const float*)d_in[12];
  float* out = (float*)d_out;

  char* ws = (char*)d_ws;
  size_t off = 0;
  auto alloc = [&](size_t bytes) -> void* {
    void* p = ws + off;
    off += (bytes + 255) & ~(size_t)255;
    return p;
  };
  unsigned short* xn    = (unsigned short*)alloc((size_t)NTOK * D_ * 2);
  unsigned short* qkvb  = (unsigned short*)alloc((size_t)NTOK * 3 * D_ * 2);
  unsigned short* w_inb = (unsigned short*)alloc((size_t)3 * D_ * D_ * 2);
  unsigned short* w_outb= (unsigned short*)alloc((size_t)D_ * D_ * 2);
  unsigned short* w1b   = (unsigned short*)alloc((size_t)MLP_ * D_ * 2);
  unsigned short* w2b   = (unsigned short*)alloc((size_t)D_ * MLP_ * 2);
  unsigned short* Qg    = (unsigned short*)alloc((size_t)B_ * H_ * QG * 64 * 2);
  unsigned short* Kh    = (unsigned short*)alloc((size_t)B_ * H_ * T_ * 64 * 2);
  unsigned short* Vt    = (unsigned short*)alloc((size_t)B_ * H_ * 64 * T_ * 2);
  unsigned short* S     = (unsigned short*)alloc((size_t)B_ * H_ * QG * T_ * 2);
  float*          Og    = (float*)         alloc((size_t)B_ * H_ * QG * 64 * 4);
  unsigned short* o     = (unsigned short*)alloc((size_t)NTOK * D_ * 2);
  float*          x1    = (float*)         alloc((size_t)NTOK * D_ * 4);
  unsigned short* xn2   = (unsigned short*)alloc((size_t)NTOK * D_ * 2);
  unsigned short* h     = (unsigned short*)alloc((size_t)NTOK * MLP_ * 2);

  // 1. weight casts
  cast_bf16_kernel<<<3072, 256, 0, stream>>>(w_in,  w_inb,  3 * D_ * D_ / 4);
  cast_bf16_kernel<<<1024, 256, 0, stream>>>(w_out, w_outb, D_ * D_ / 4);
  cast_bf16_kernel<<<4096, 256, 0, stream>>>(w1,    w1b,    MLP_ * D_ / 4);
  cast_bf16_kernel<<<4096, 256, 0, stream>>>(w2,    w2b,    D_ * MLP_ / 4);

  // 2. LN1
  ln_kernel<<<NTOK, 256, 0, stream>>>(x, ln1_g, ln1_b, xn);

  // 3. QKV = xn @ w_in^T + b_in -> bf16 [4096, 3072]  (super-tile swizzle)
  gemm_kernel<6, 2><<<dim3(24 * 32, 1, 1), 256, 0, stream>>>(
      xn, D_, 0, w_inb, D_, 0, qkvb, 3 * D_, 0, b_in, nullptr,
      NTOK, 3 * D_, D_, 1.0f, 24, 32);

  // 4. split heads
  qg_kernel<<<2048, 256, 0, stream>>>(qkvb, Qg);
  kh_kernel<<<16384, 256, 0, stream>>>(qkvb, Kh);
  vtrans_kernel<<<1024, 256, 0, stream>>>(qkvb, Vt);

  // 5. S = Qg Kh^T / 8   (batched over 32 bh)
  gemm_kernel<3, 0><<<dim3(32, 1, 32), 256, 0, stream>>>(
      Qg, 64, (size_t)QG * 64, Kh, 64, (size_t)T_ * 64,
      S, T_, (size_t)QG * T_, nullptr, nullptr,
      QG, T_, 64, 0.125f, 16, 2);

  // 6. softmax rows
  softmax_kernel<<<B_ * H_ * QG, 256, 0, stream>>>(S);

  // 7. Og = P V  (split-K x4, f32 atomic accumulate)
  hipMemsetAsync(Og, 0, (size_t)B_ * H_ * QG * 64 * 4, stream);
  gemm_kernel<5, 0><<<dim3(2, 1, 128), 256, 0, stream>>>(
      S, T_, (size_t)QG * T_, Vt, T_, (size_t)64 * T_,
      Og, 64, (size_t)QG * 64, nullptr, nullptr,
      QG, 64, 512, 1.0f, 1, 2);

  // 8. assemble o
  assemble_o_kernel<<<16384, 256, 0, stream>>>(qkvb, Og, o);

  // 9. x1 = x + o @ w_out^T + b_out -> f32  (y-fast: A reuse per XCD)
  gemm_kernel<1, 1><<<dim3(8 * 32, 1, 1), 256, 0, stream>>>(
      o, D_, 0, w_outb, D_, 0, x1, D_, 0, b_out, x,
      NTOK, D_, D_, 1.0f, 8, 32);

  // 10. LN2
  ln_kernel<<<NTOK, 256, 0, stream>>>(x1, ln2_g, ln2_b, xn2);

  // 11. h = gelu(xn2 @ w1^T + b1) -> bf16 [4096, 4096]  (super-tile)
  gemm_kernel<2, 2><<<dim3(32 * 32, 1, 1), 256, 0, stream>>>(
      xn2, D_, 0, w1b, D_, 0, h, MLP_, 0, b1, nullptr,
      NTOK, MLP_, D_, 1.0f, 32, 32);

  // 12. out = x1 + h @ w2^T + b2 -> f32  (y-fast: A reuse per XCD)
  gemm_kernel<1, 1><<<dim3(8 * 32, 1, 1), 256, 0, stream>>>(
      h, MLP_, 0, w2b, MLP_, 0, out, D_, 0, b2, x1,
      NTOK, D_, MLP_, 1.0f, 8, 32);
}